// Round 8
// baseline (346.446 us; speedup 1.0000x reference)
//
#include <hip/hip_runtime.h>
#include <stdint.h>

// Problem constants
#define B_  1024
#define D_  512
#define K_  255
#define L_  256
#define C_  80

typedef __attribute__((ext_vector_type(8))) short bf16x8;
typedef __attribute__((ext_vector_type(4))) float f32x4;
typedef __attribute__((ext_vector_type(8))) short short8;

// async global->LDS, 16B per lane; dst must be wave-uniform base + lane*16.
#define GLD(gsrc, ldst) \
  __builtin_amdgcn_global_load_lds((const __attribute__((address_space(1))) void*)(gsrc), \
                                   (__attribute__((address_space(3))) void*)(ldst), 16, 0, 0)

__device__ __forceinline__ short cvt_bf16(float f) {
    unsigned u = __float_as_uint(f);
    u += 0x7FFFu + ((u >> 16) & 1u);
    return (short)(u >> 16);
}

// ---------------------------------------------------------------------------
// Kernel 1: convert W (20480x512) + x (1024x512) fp32->bf16, AND normalize
// ne rows -> bf16 neb (256 rows; row 255 zeroed).
// ---------------------------------------------------------------------------
__global__ __launch_bounds__(256) void convert_kernel(const float* __restrict__ w,
                                                      const float* __restrict__ x,
                                                      const float* __restrict__ ne,
                                                      short* __restrict__ wb,
                                                      short* __restrict__ xb,
                                                      short* __restrict__ neb) {
    __shared__ float red[256];
    const int tid = threadIdx.x;
    if (blockIdx.x < 2048) {
        size_t i0 = (size_t)blockIdx.x * 256 + tid;
        const size_t stride = 2048u * 256u;
        for (size_t v = i0; v < 1310720u; v += stride) {
            float4 a = ((const float4*)w)[v * 2];
            float4 b = ((const float4*)w)[v * 2 + 1];
            short8 o;
            o[0] = cvt_bf16(a.x); o[1] = cvt_bf16(a.y); o[2] = cvt_bf16(a.z); o[3] = cvt_bf16(a.w);
            o[4] = cvt_bf16(b.x); o[5] = cvt_bf16(b.y); o[6] = cvt_bf16(b.z); o[7] = cvt_bf16(b.w);
            ((short8*)wb)[v] = o;
        }
        for (size_t v = i0; v < 65536u; v += stride) {
            float4 a = ((const float4*)x)[v * 2];
            float4 b = ((const float4*)x)[v * 2 + 1];
            short8 o;
            o[0] = cvt_bf16(a.x); o[1] = cvt_bf16(a.y); o[2] = cvt_bf16(a.z); o[3] = cvt_bf16(a.w);
            o[4] = cvt_bf16(b.x); o[5] = cvt_bf16(b.y); o[6] = cvt_bf16(b.z); o[7] = cvt_bf16(b.w);
            ((short8*)xb)[v] = o;
        }
    } else {
        const int row = blockIdx.x - 2048;  // 0..255
        if (row == 255) {
            ((unsigned*)(neb + 255 * 512))[tid] = 0u;  // pad row = zeros
            return;
        }
        const float2* nr = (const float2*)(ne + (size_t)row * 512);
        float2 a = nr[tid];
        red[tid] = a.x * a.x + a.y * a.y;
        __syncthreads();
        #pragma unroll
        for (int s = 128; s > 0; s >>= 1) {
            if (tid < s) red[tid] += red[tid + s];
            __syncthreads();
        }
        float inv = rsqrtf(red[0]);
        unsigned lo = (unsigned short)cvt_bf16(a.x * inv);
        unsigned hi = (unsigned short)cvt_bf16(a.y * inv);
        ((unsigned*)(neb + (size_t)row * 512))[tid] = lo | (hi << 16);
    }
}

// ---------------------------------------------------------------------------
// Kernel 2: sim GEMM: out1[b,k] = sigmoid(xb[b,:]·neb[k,:]). 64x64 tiles.
// ---------------------------------------------------------------------------
__global__ __launch_bounds__(256) void simgemm_kernel(const short* __restrict__ xb,
                                                      const short* __restrict__ neb,
                                                      float* __restrict__ out1) {
    __shared__ __align__(16) short Ald[512 * 8];
    __shared__ __align__(16) short Bld[512 * 8];
    const int tid = threadIdx.x;
    const int lane = tid & 63, wave = tid >> 6;
    const int q = lane >> 4, r = lane & 15;
    const int mt = blockIdx.x >> 2;
    const int nt = blockIdx.x & 3;

    f32x4 acc[4];
    #pragma unroll
    for (int nf = 0; nf < 4; ++nf) acc[nf] = (f32x4){0.f, 0.f, 0.f, 0.f};

    const bf16x8* Av = (const bf16x8*)Ald;
    const bf16x8* Bv = (const bf16x8*)Bld;

    for (int kb = 0; kb < 8; ++kb) {
        __syncthreads();
        #pragma unroll
        for (int j = 0; j < 2; ++j) {
            int ph = j * 256 + tid, rr = ph >> 3, g = (ph & 7) ^ (rr & 7);
            GLD(xb + ((size_t)(mt * 64 + rr) * D_ + kb * 64 + g * 8), Ald + ph * 8);
        }
        #pragma unroll
        for (int j = 0; j < 2; ++j) {
            int ph = j * 256 + tid, cc = ph >> 3, g = (ph & 7) ^ (cc & 7);
            GLD(neb + ((size_t)(nt * 64 + cc) * D_ + kb * 64 + g * 8), Bld + ph * 8);
        }
        __syncthreads();
        #pragma unroll
        for (int ks = 0; ks < 2; ++ks) {
            const int g = ks * 4 + q;
            int rl = wave * 16 + r;
            bf16x8 af = Av[rl * 8 + (g ^ (rl & 7))];
            #pragma unroll
            for (int nf = 0; nf < 4; ++nf) {
                int cl = nf * 16 + r;
                bf16x8 bfr = Bv[cl * 8 + (g ^ (cl & 7))];
                acc[nf] = __builtin_amdgcn_mfma_f32_16x16x32_bf16(af, bfr, acc[nf], 0, 0, 0);
            }
        }
    }
    #pragma unroll
    for (int nf = 0; nf < 4; ++nf) {
        int gcol = nt * 64 + nf * 16 + r;
        if (gcol < K_) {
            #pragma unroll
            for (int i = 0; i < 4; ++i) {
                int grow = mt * 64 + wave * 16 + q * 4 + i;
                out1[(size_t)grow * K_ + gcol] = 1.f / (1.f + __expf(-acc[nf][i]));
            }
        }
    }
}

// ---------------------------------------------------------------------------
// Kernel 3: leaf probabilities from out1 sigmoids. Block = batch row.
// ---------------------------------------------------------------------------
__global__ __launch_bounds__(256) void leafprob_kernel(const float* __restrict__ out1,
                                                       float* __restrict__ p_ws) {
    __shared__ float ss[K_];
    const int b = blockIdx.x, t = threadIdx.x;
    if (t < K_) ss[t] = out1[(size_t)b * K_ + t];
    __syncthreads();
    float prob = 1.f;
    int node = 0;
    #pragma unroll
    for (int d = 0; d < 8; ++d) {
        int bit = (t >> (7 - d)) & 1;
        float s = ss[node];
        prob *= bit ? (1.f - s) : s;
        node = 2 * node + 1 + bit;
    }
    p_ws[(size_t)b * L_ + t] = prob;
}

// ---------------------------------------------------------------------------
// Kernel 4: main GEMM — AITER-style dataflow K-loop. ZERO LDS, ZERO barriers,
// frags streamed global(L1/L2)->VGPR with EXPLICIT ping-pong prefetch:
// unit u = (ks,li); unit u+1's B-frags (and next ks's A-frags) are loaded
// into the other register buffer BEFORE unit u's MFMAs, forcing the compiler
// to keep ~7 loads in flight with fine-grained vmcnt (never 0) — the r6
// failure (VGPR=60, loads sunk to uses, latency-serialized) is structurally
// impossible here. B-frags re-read by the block's 4 waves hit L1.
// Fold p_l*dec per unit (linearity); accumulate out0 via atomicAdd (out0
// zeroed by memset in kernel_launch) — partial buffer + reduce kernel gone.
// Grid = mt(8) x lp(128) = 1024 blocks; same-lp -> same XCD (B slab L2-hot).
// Regs ~155 -> (256,3): 12 waves/CU, no LDS limit.
// ---------------------------------------------------------------------------
__global__ __launch_bounds__(256, 3) void gemm_kernel(const short* __restrict__ xb,
                                                      const short* __restrict__ wb,
                                                      const float* __restrict__ p,
                                                      const float* __restrict__ lb,
                                                      float* __restrict__ out0) {
    const int tid  = threadIdx.x;
    const int lane = tid & 63, wave = tid >> 6;
    const int q = lane >> 4, r = lane & 15;
    const int wrow = wave * 32;
    const int lp = blockIdx.x & 127;  // 128 leaf-pairs
    const int mt = blockIdx.x >> 7;   // 8 m-tiles

    // p weights in registers: this lane's 8 rows x 2 leaves
    float pv[2][2][4];  // [mf][li][i]
    #pragma unroll
    for (int mf = 0; mf < 2; ++mf)
        #pragma unroll
        for (int i = 0; i < 4; ++i) {
            const float* pr = p + (size_t)(mt * 128 + wrow + mf * 16 + q * 4 + i) * L_ + 2 * lp;
            pv[mf][0][i] = pr[0];
            pv[mf][1][i] = pr[1];
        }

    const short* Ab = xb + (size_t)(mt * 128 + wrow) * D_;
    const short* Bb = wb + (size_t)lp * 160 * D_;
    const int voff = r * D_ + q * 8;  // lane-variant frag offset

    f32x4 outacc[2][5];
    #pragma unroll
    for (int mf = 0; mf < 2; ++mf)
        #pragma unroll
        for (int nf = 0; nf < 5; ++nf)
            outacc[mf][nf] = (f32x4){0.f, 0.f, 0.f, 0.f};

    const f32x4 z = {0.f, 0.f, 0.f, 0.f};

    bf16x8 afb[2][2];   // A frags, ping-pong by ks&1
    bf16x8 bfb[2][5];   // B frags, ping-pong by unit&1

    // prologue: af(ks=0), bfr(unit 0 = ks0,li0)
    #pragma unroll
    for (int mf = 0; mf < 2; ++mf)
        afb[0][mf] = *(const bf16x8*)(Ab + mf * 16 * D_ + voff);
    #pragma unroll
    for (int nf = 0; nf < 5; ++nf)
        bfb[0][nf] = *(const bf16x8*)(Bb + nf * 16 * D_ + voff);

    #pragma unroll 4
    for (int u = 0; u < 32; ++u) {
        const int ks = u >> 1, li = u & 1;
        const int cur = u & 1, nxt = cur ^ 1;

        // prefetch unit u+1's B frags into the other buffer
        if (u < 31) {
            const int ks1 = (u + 1) >> 1, li1 = (u + 1) & 1;
            const short* bp = Bb + (size_t)(li1 * 80) * D_ + ks1 * 32 + voff;
            #pragma unroll
            for (int nf = 0; nf < 5; ++nf)
                bfb[nxt][nf] = *(const bf16x8*)(bp + nf * 16 * D_);
        }
        // on even units, prefetch next ks's A frags
        if (li == 0 && ks < 15) {
            #pragma unroll
            for (int mf = 0; mf < 2; ++mf)
                afb[(ks + 1) & 1][mf] = *(const bf16x8*)(Ab + mf * 16 * D_ + (ks + 1) * 32 + voff);
        }

        // compute unit u: 10 MFMA + 20 folds
        #pragma unroll
        for (int mf = 0; mf < 2; ++mf) {
            f32x4 d[5];
            #pragma unroll
            for (int nf = 0; nf < 5; ++nf)
                d[nf] = __builtin_amdgcn_mfma_f32_16x16x32_bf16(
                    afb[ks & 1][mf], bfb[cur][nf], z, 0, 0, 0);
            #pragma unroll
            for (int nf = 0; nf < 5; ++nf)
                #pragma unroll
                for (int i = 0; i < 4; ++i)
                    outacc[mf][nf][i] += pv[mf][li][i] * d[nf][i];
        }
    }

    // epilogue: atomically accumulate p-weighted result + bias into out0
    const float* lbb = lb + lp * 160;
    #pragma unroll
    for (int mf = 0; mf < 2; ++mf)
        #pragma unroll
        for (int nf = 0; nf < 5; ++nf) {
            int col = nf * 16 + r;
            float b0 = lbb[col], b1 = lbb[80 + col];
            #pragma unroll
            for (int i = 0; i < 4; ++i) {
                int row = mt * 128 + wrow + mf * 16 + q * 4 + i;
                float v = outacc[mf][nf][i] + pv[mf][0][i] * b0 + pv[mf][1][i] * b1;
                atomicAdd(&out0[(size_t)row * C_ + col], v);
            }
        }
}

// ---------------------------------------------------------------------------
extern "C" void kernel_launch(void* const* d_in, const int* in_sizes, int n_in,
                              void* d_out, int out_size, void* d_ws, size_t ws_size,
                              hipStream_t stream) {
    const float* x  = (const float*)d_in[0];  // 1024x512
    const float* ne = (const float*)d_in[1];  // 255x512
    const float* lW = (const float*)d_in[2];  // 20480x512
    const float* lb = (const float*)d_in[3];  // 20480
    // d_in[4] res_path: deterministic structure, traversed directly

    float* out0 = (float*)d_out;            // 1024x80
    float* out1 = out0 + (size_t)B_ * C_;   // 1024x255

    char* ws = (char*)d_ws;
    short* xb   = (short*)ws;                              // 1 MB
    short* neb  = (short*)(ws + (1u << 20));               // 256 KB
    float* p_ws = (float*)(ws + (1u << 20) + (1u << 18));  // 1 MB
    short* wb   = (short*)(ws + (9u << 18));               // 20 MB @ 2.25 MB

    hipMemsetAsync(out0, 0, (size_t)B_ * C_ * sizeof(float), stream);  // atomic target
    convert_kernel<<<2304, 256, 0, stream>>>(lW, x, ne, wb, xb, neb);
    simgemm_kernel<<<64, 256, 0, stream>>>(xb, neb, out1);
    leafprob_kernel<<<B_, 256, 0, stream>>>(out1, p_ws);
    gemm_kernel<<<1024, 256, 0, stream>>>(xb, wb, p_ws, lb, out0);
}

// Round 9
// 137.543 us; speedup vs baseline: 2.5188x; 2.5188x over previous
//
#include <hip/hip_runtime.h>
#include <stdint.h>

// Problem constants
#define B_  1024
#define D_  512
#define K_  255
#define L_  256
#define C_  80

typedef __attribute__((ext_vector_type(8))) short bf16x8;
typedef __attribute__((ext_vector_type(4))) float f32x4;
typedef __attribute__((ext_vector_type(8))) short short8;

// async global->LDS, 16B per lane; dst must be wave-uniform base + lane*16.
#define GLD(gsrc, ldst) \
  __builtin_amdgcn_global_load_lds((const __attribute__((address_space(1))) void*)(gsrc), \
                                   (__attribute__((address_space(3))) void*)(ldst), 16, 0, 0)

__device__ __forceinline__ short cvt_bf16(float f) {
    unsigned u = __float_as_uint(f);
    u += 0x7FFFu + ((u >> 16) & 1u);
    return (short)(u >> 16);
}

// ---------------------------------------------------------------------------
// Kernel 1: convert W (20480x512) + x (1024x512) fp32->bf16, AND normalize
// ne rows -> bf16 neb (256 rows; row 255 zeroed).
// ---------------------------------------------------------------------------
__global__ __launch_bounds__(256) void convert_kernel(const float* __restrict__ w,
                                                      const float* __restrict__ x,
                                                      const float* __restrict__ ne,
                                                      short* __restrict__ wb,
                                                      short* __restrict__ xb,
                                                      short* __restrict__ neb) {
    __shared__ float red[256];
    const int tid = threadIdx.x;
    if (blockIdx.x < 2048) {
        size_t i0 = (size_t)blockIdx.x * 256 + tid;
        const size_t stride = 2048u * 256u;
        for (size_t v = i0; v < 1310720u; v += stride) {
            float4 a = ((const float4*)w)[v * 2];
            float4 b = ((const float4*)w)[v * 2 + 1];
            short8 o;
            o[0] = cvt_bf16(a.x); o[1] = cvt_bf16(a.y); o[2] = cvt_bf16(a.z); o[3] = cvt_bf16(a.w);
            o[4] = cvt_bf16(b.x); o[5] = cvt_bf16(b.y); o[6] = cvt_bf16(b.z); o[7] = cvt_bf16(b.w);
            ((short8*)wb)[v] = o;
        }
        for (size_t v = i0; v < 65536u; v += stride) {
            float4 a = ((const float4*)x)[v * 2];
            float4 b = ((const float4*)x)[v * 2 + 1];
            short8 o;
            o[0] = cvt_bf16(a.x); o[1] = cvt_bf16(a.y); o[2] = cvt_bf16(a.z); o[3] = cvt_bf16(a.w);
            o[4] = cvt_bf16(b.x); o[5] = cvt_bf16(b.y); o[6] = cvt_bf16(b.z); o[7] = cvt_bf16(b.w);
            ((short8*)xb)[v] = o;
        }
    } else {
        const int row = blockIdx.x - 2048;  // 0..255
        if (row == 255) {
            ((unsigned*)(neb + 255 * 512))[tid] = 0u;  // pad row = zeros
            return;
        }
        const float2* nr = (const float2*)(ne + (size_t)row * 512);
        float2 a = nr[tid];
        red[tid] = a.x * a.x + a.y * a.y;
        __syncthreads();
        #pragma unroll
        for (int s = 128; s > 0; s >>= 1) {
            if (tid < s) red[tid] += red[tid + s];
            __syncthreads();
        }
        float inv = rsqrtf(red[0]);
        unsigned lo = (unsigned short)cvt_bf16(a.x * inv);
        unsigned hi = (unsigned short)cvt_bf16(a.y * inv);
        ((unsigned*)(neb + (size_t)row * 512))[tid] = lo | (hi << 16);
    }
}

// ---------------------------------------------------------------------------
// Kernel 2: sim GEMM: out1[b,k] = sigmoid(xb[b,:]·neb[k,:]). 64x64 tiles.
// ---------------------------------------------------------------------------
__global__ __launch_bounds__(256) void simgemm_kernel(const short* __restrict__ xb,
                                                      const short* __restrict__ neb,
                                                      float* __restrict__ out1) {
    __shared__ __align__(16) short Ald[512 * 8];
    __shared__ __align__(16) short Bld[512 * 8];
    const int tid = threadIdx.x;
    const int lane = tid & 63, wave = tid >> 6;
    const int q = lane >> 4, r = lane & 15;
    const int mt = blockIdx.x >> 2;
    const int nt = blockIdx.x & 3;

    f32x4 acc[4];
    #pragma unroll
    for (int nf = 0; nf < 4; ++nf) acc[nf] = (f32x4){0.f, 0.f, 0.f, 0.f};

    const bf16x8* Av = (const bf16x8*)Ald;
    const bf16x8* Bv = (const bf16x8*)Bld;

    for (int kb = 0; kb < 8; ++kb) {
        __syncthreads();
        #pragma unroll
        for (int j = 0; j < 2; ++j) {
            int ph = j * 256 + tid, rr = ph >> 3, g = (ph & 7) ^ (rr & 7);
            GLD(xb + ((size_t)(mt * 64 + rr) * D_ + kb * 64 + g * 8), Ald + ph * 8);
        }
        #pragma unroll
        for (int j = 0; j < 2; ++j) {
            int ph = j * 256 + tid, cc = ph >> 3, g = (ph & 7) ^ (cc & 7);
            GLD(neb + ((size_t)(nt * 64 + cc) * D_ + kb * 64 + g * 8), Bld + ph * 8);
        }
        __syncthreads();
        #pragma unroll
        for (int ks = 0; ks < 2; ++ks) {
            const int g = ks * 4 + q;
            int rl = wave * 16 + r;
            bf16x8 af = Av[rl * 8 + (g ^ (rl & 7))];
            #pragma unroll
            for (int nf = 0; nf < 4; ++nf) {
                int cl = nf * 16 + r;
                bf16x8 bfr = Bv[cl * 8 + (g ^ (cl & 7))];
                acc[nf] = __builtin_amdgcn_mfma_f32_16x16x32_bf16(af, bfr, acc[nf], 0, 0, 0);
            }
        }
    }
    #pragma unroll
    for (int nf = 0; nf < 4; ++nf) {
        int gcol = nt * 64 + nf * 16 + r;
        if (gcol < K_) {
            #pragma unroll
            for (int i = 0; i < 4; ++i) {
                int grow = mt * 64 + wave * 16 + q * 4 + i;
                out1[(size_t)grow * K_ + gcol] = 1.f / (1.f + __expf(-acc[nf][i]));
            }
        }
    }
}

// ---------------------------------------------------------------------------
// Kernel 3: leaf probabilities from out1 sigmoids. Block = batch row.
// ---------------------------------------------------------------------------
__global__ __launch_bounds__(256) void leafprob_kernel(const float* __restrict__ out1,
                                                       float* __restrict__ p_ws) {
    __shared__ float ss[K_];
    const int b = blockIdx.x, t = threadIdx.x;
    if (t < K_) ss[t] = out1[(size_t)b * K_ + t];
    __syncthreads();
    float prob = 1.f;
    int node = 0;
    #pragma unroll
    for (int d = 0; d < 8; ++d) {
        int bit = (t >> (7 - d)) & 1;
        float s = ss[node];
        prob *= bit ? (1.f - s) : s;
        node = 2 * node + 1 + bit;
    }
    p_ws[(size_t)b * L_ + t] = prob;
}

// ---------------------------------------------------------------------------
// Kernel 4: main GEMM — r5 staging/barriers, NEW wave mapping for LDS-read
// throughput: wave = 64 rows x 80 cols of ONE leaf (wave w: rows (w&1)*64,
// leaf w>>1), dec[4][5] accumulated over full K — no per-stage fold.
// Per stage per wave: 18 ds_read_b128 feed 40 MFMA (ratio 2.2:1 vs r5's
// 0.83:1) and zero fold-VALU in the K-loop. Epilogue: leaf-1 waves fold
// p*(dec+b) into LDS scratch (union with staging), leaf-0 waves add + store
// partial. Block tile unchanged: 128 rows x 2 leaves; grid = mt(8) x lp(128)
// = 1024 blocks; same-lp -> same XCD (B slab L2-resident).
// LDS: max(16K A + 20K B, 41.5K scratch) + p/b ~= 44 KB -> 3 blocks/CU.
// ---------------------------------------------------------------------------
__global__ __launch_bounds__(256, 2) void gemm_kernel(const short* __restrict__ xb,
                                                      const short* __restrict__ wb,
                                                      const float* __restrict__ p,
                                                      const float* __restrict__ lb,
                                                      float* __restrict__ partial) {
    __shared__ __align__(16) union {
        struct { short A[1024 * 8]; short Bst[1280 * 8]; } s;  // 16 KB + 20 KB
        float scr[2][64][81];                                   // 41.5 KB epilogue scratch
    } u;
    __shared__ float p_ld[128][2];
    __shared__ float b_ld[160];

    const int tid = threadIdx.x;
    const int lane = tid & 63, wave = tid >> 6;
    const int q = lane >> 4, r = lane & 15;
    const int li = wave >> 1;         // leaf within pair
    const int wr = (wave & 1) * 64;   // wave row base
    const int lp = blockIdx.x & 127;  // 128 leaf-pairs
    const int mt = blockIdx.x >> 7;   // 8 m-tiles

    if (tid < 128) {
        p_ld[tid][0] = p[(size_t)(mt * 128 + tid) * L_ + 2 * lp];
        p_ld[tid][1] = p[(size_t)(mt * 128 + tid) * L_ + 2 * lp + 1];
    }
    if (tid < 160) b_ld[tid] = lb[lp * 160 + tid];

    f32x4 dec[4][5];
    #pragma unroll
    for (int mf = 0; mf < 4; ++mf)
        #pragma unroll
        for (int nf = 0; nf < 5; ++nf)
            dec[mf][nf] = (f32x4){0.f, 0.f, 0.f, 0.f};

    const bf16x8* Av = (const bf16x8*)u.s.A;
    const bf16x8* Bv = (const bf16x8*)u.s.Bst;

    for (int kb = 0; kb < 8; ++kb) {
        __syncthreads();  // previous stage's LDS reads done before overwrite
        // stage A: 1024 granules (128 rows x 8), 4 per thread
        #pragma unroll
        for (int j = 0; j < 4; ++j) {
            int ph = j * 256 + tid;
            int rr = ph >> 3;
            int g  = (ph & 7) ^ (rr & 7);
            GLD(xb + ((size_t)(mt * 128 + rr) * D_ + kb * 64 + g * 8), u.s.A + ph * 8);
        }
        // stage B: 1280 granules (160 rows = 2 leaves x 80), 5 per thread
        #pragma unroll
        for (int j = 0; j < 5; ++j) {
            int ph = j * 256 + tid;
            int cc = ph >> 3;
            int g  = (ph & 7) ^ (cc & 7);
            GLD(wb + ((size_t)(lp * 160 + cc) * D_ + kb * 64 + g * 8), u.s.Bst + ph * 8);
        }
        __syncthreads();  // drains vmcnt(0): global_load_lds complete

        #pragma unroll
        for (int ks = 0; ks < 2; ++ks) {
            const int g = ks * 4 + q;
            bf16x8 af[4];
            #pragma unroll
            for (int mf = 0; mf < 4; ++mf) {
                int rl = wr + mf * 16 + r;
                af[mf] = Av[rl * 8 + (g ^ (rl & 7))];
            }
            #pragma unroll
            for (int nf = 0; nf < 5; ++nf) {
                int cl = li * 80 + nf * 16 + r;
                bf16x8 bfr = Bv[cl * 8 + (g ^ (cl & 7))];
                #pragma unroll
                for (int mf = 0; mf < 4; ++mf)
                    dec[mf][nf] = __builtin_amdgcn_mfma_f32_16x16x32_bf16(
                        af[mf], bfr, dec[mf][nf], 0, 0, 0);
            }
        }
    }

    // epilogue: fold p*(dec+bias) per leaf; combine the two leaves via LDS.
    float pv[4][4];  // p for this lane's 16 rows, this wave's leaf
    #pragma unroll
    for (int mf = 0; mf < 4; ++mf)
        #pragma unroll
        for (int i = 0; i < 4; ++i)
            pv[mf][i] = p_ld[wr + mf * 16 + q * 4 + i][li];

    __syncthreads();  // staging reads done; safe to reuse LDS as scratch

    if (li == 1) {  // waves 2,3: write folded leaf-1 values to scratch
        #pragma unroll
        for (int mf = 0; mf < 4; ++mf)
            #pragma unroll
            for (int nf = 0; nf < 5; ++nf) {
                int col = nf * 16 + r;
                float bv = b_ld[80 + col];
                #pragma unroll
                for (int i = 0; i < 4; ++i) {
                    int rowl = mf * 16 + q * 4 + i;
                    u.scr[wave & 1][rowl][col] = pv[mf][i] * (dec[mf][nf][i] + bv);
                }
            }
    }
    __syncthreads();
    if (li == 0) {  // waves 0,1: add leaf-0 fold + scratch, store partial
        const size_t rbase = (size_t)lp * B_ + mt * 128;
        #pragma unroll
        for (int mf = 0; mf < 4; ++mf)
            #pragma unroll
            for (int nf = 0; nf < 5; ++nf) {
                int col = nf * 16 + r;
                float bv = b_ld[col];
                #pragma unroll
                for (int i = 0; i < 4; ++i) {
                    int rowl = mf * 16 + q * 4 + i;
                    float v = pv[mf][i] * (dec[mf][nf][i] + bv) + u.scr[wave & 1][rowl][col];
                    partial[(rbase + wr + rowl) * C_ + col] = v;
                }
            }
    }
}

// ---------------------------------------------------------------------------
// Kernel 5: reduce 128 lp partials -> out0 (1024x80), float4 per thread
// ---------------------------------------------------------------------------
__global__ __launch_bounds__(256) void reduce_kernel(const float* __restrict__ partial,
                                                     float* __restrict__ out0) {
    int idx = blockIdx.x * 256 + threadIdx.x;  // < 20480 float4s
    const float4* p4 = (const float4*)partial;
    float4 s = {0.f, 0.f, 0.f, 0.f};
    #pragma unroll 8
    for (int j = 0; j < 128; ++j) {
        float4 v = p4[(size_t)j * (B_ * C_ / 4) + idx];
        s.x += v.x; s.y += v.y; s.z += v.z; s.w += v.w;
    }
    ((float4*)out0)[idx] = s;
}

// ---------------------------------------------------------------------------
extern "C" void kernel_launch(void* const* d_in, const int* in_sizes, int n_in,
                              void* d_out, int out_size, void* d_ws, size_t ws_size,
                              hipStream_t stream) {
    const float* x  = (const float*)d_in[0];  // 1024x512
    const float* ne = (const float*)d_in[1];  // 255x512
    const float* lW = (const float*)d_in[2];  // 20480x512
    const float* lb = (const float*)d_in[3];  // 20480
    // d_in[4] res_path: deterministic structure, traversed directly

    float* out0 = (float*)d_out;            // 1024x80
    float* out1 = out0 + (size_t)B_ * C_;   // 1024x255

    char* ws = (char*)d_ws;
    short* xb      = (short*)ws;                             // 1 MB
    short* neb     = (short*)(ws + (1u << 20));              // 256 KB
    float* p_ws    = (float*)(ws + (1u << 20) + (1u << 18)); // 1 MB
    short* wb      = (short*)(ws + (9u << 18));              // 20 MB @ 2.25 MB
    float* partial = (float*)(ws + (24u << 20));             // 40 MB (128x1024x80)

    convert_kernel<<<2304, 256, 0, stream>>>(lW, x, ne, wb, xb, neb);
    simgemm_kernel<<<64, 256, 0, stream>>>(xb, neb, out1);
    leafprob_kernel<<<B_, 256, 0, stream>>>(out1, p_ws);
    gemm_kernel<<<1024, 256, 0, stream>>>(xb, wb, p_ws, lb, partial);
    reduce_kernel<<<B_ * C_ / 1024, 256, 0, stream>>>(partial, out0);
}